// Round 17
// baseline (156.979 us; speedup 1.0000x reference)
//
#include <hip/hip_runtime.h>

// deepSNN forward, layer_idx=3 path, fp32 exact, element-sparse conv2.
// x:(20,6,160,160) w1:(30,6,4,4) w2:(250,30,3,3) w3:(200,250,3,3)
// pipeline: pad2->conv1->fire(1)->pool2x2 -> pad2->conv2->fire(1)->pool3x3
//           -> pad2->conv3->fire(25) -> out = [spk | pot] (2 x 20*200*29*29 fp32)
//
// r16 post-mortem: UB pre-pass regressed conv2 35->47.7us — it duplicated the
// scan it was meant to avoid; conv2 is scan-bound (75 serial word tests + 75
// ds reads per wave), not gather-bound (~4% word density). r17: revert to the
// exact r14 config (best total 142.7) + ONE conv2 change: 25-bit per-window
// nonzero-word bitmap built once per block (LDS atomicOr); wave loop becomes
// ctz-walk over the bitmap with a switch into the SAME compile-time (dr,ds)
// pairwise gather cases (r10's lesson: never make dr dynamic).

#define OUT_HALF 3364000  // 20*200*29*29
#define MASK_PLANE 128000 // 20*80*80 (u32 elements per plane)
#define T_FLOATS 168200   // 200*29*29 floats per t per half

typedef float v2f __attribute__((ext_vector_type(2)));

// ---------------- conv1(4x4)+fire(1)+pool2x2 -> mask1 (blocks 0..1499)
//                  + w2 transpose + flags2 zero   (blocks 1500..1763)
// conv1 block: (t, 5 row-tiles, 5 col-tiles, 3 oc-thirds), 256 thr.
// mask1[h*MASK_PLANE + (t*80+r)*80+c] bits 0..9 = spikes of oc h*10..h*10+9.
// Input LDS: [c][row][perm(lc)], row stride 40, perm(lc)=lc/2+(lc&1)*20 ->
// compute reads hit 2 lanes/bank (free). Weights: wave-uniform float4 loads.
// [r14 version, best measured ~43.3us: VGPR 52, no spill, 546k conflicts]
__global__ __launch_bounds__(256, 4) void k_conv1(const float* __restrict__ x,
                                                  const float* __restrict__ w1,
                                                  const float* __restrict__ w2,
                                                  float* __restrict__ w2t,
                                                  unsigned int* __restrict__ mask1,
                                                  unsigned int* __restrict__ flags2) {
    if (blockIdx.x >= 1500) {  // transpose part: w2[oc][ck] -> w2t[ck][oc]
        int tb = blockIdx.x - 1500;
        int tid = threadIdx.x;
        if (tb == 0)
            for (int i = tid; i < 540; i += 256) flags2[i] = 0u;
        int idx = tb * 256 + tid;
        if (idx < 67500) {
            int oc = idx / 270, ck = idx % 270;
            w2t[ck * 250 + oc] = w2[idx];
        }
        return;
    }

    __shared__ float in_lds[6 * 35 * 40];  // 33600 B

    int b = blockIdx.x;
    int h = b % 3;     b /= 3;  // oc third: oc h*10 .. h*10+9
    int colt = b % 5;  b /= 5;
    int rowt = b % 5;  b /= 5;
    int t = b;
    int ph0 = rowt * 16, pw0 = colt * 16;
    int i0 = 2 * ph0, j0 = 2 * pw0;  // padded-164 coords of tile conv origin
    int tid = threadIdx.x;

    // staging: 210 rows x 10 float4 chunks; chunks are fully in- or out-of-
    // bounds (gc0 multiple of 4, row width 160 % 4 == 0).
    for (int idx = tid; idx < 2100; idx += 256) {
        int v4 = idx % 10;
        int row = idx / 10;           // 0..209 = c*35 + rr
        int c = row / 35, rr = row % 35;
        int gr = i0 + rr - 2;
        int gc0 = j0 - 4 + 4 * v4;    // in {-4, 0, 4, ..., 160}
        float4 v; v.x = 0.f; v.y = 0.f; v.z = 0.f; v.w = 0.f;
        if ((unsigned)gr < 160u && (unsigned)gc0 < 160u)
            v = *(const float4*)&x[((t * 6 + c) * 160 + gr) * 160 + gc0];
        float* dst = &in_lds[row * 40];
        int m = 2 * v4;               // perm of lc=4v4 (even)
        dst[m]      = v.x;            // lc=4v4
        dst[m + 20] = v.y;            // lc=4v4+1 (odd)
        dst[m + 1]  = v.z;            // lc=4v4+2
        dst[m + 21] = v.w;            // lc=4v4+3
    }
    __syncthreads();

    int pw_l = tid & 15, ph_l = tid >> 4;
    int rb = 2 * ph_l;

    v2f acc01[10], acc23[10];  // positions (0,0),(0,1) and (1,0),(1,1)
#pragma unroll
    for (int o = 0; o < 10; ++o) {
        acc01[o] = (v2f)(0.f);
        acc23[o] = (v2f)(0.f);
    }

    // weights for this third: w1[(h*10+o)][c][kh][kw], float4 per (o,c,kh)
    const float4* wq = (const float4*)w1 + h * 10 * 24;

#pragma unroll 1
    for (int c = 0; c < 6; ++c) {
        // window cols cb..cb+4 (cb=2*pw_l) -> lc = 2pw_l+2+cc ->
        // perm offsets (from base+pw_l): 1, 21, 2, 22, 3
        const float* pl = &in_lds[(c * 35 + rb) * 40 + pw_l];
        float q[5][5];
#pragma unroll
        for (int r = 0; r < 5; ++r) {
            const float* pr = pl + r * 40;
            q[r][0] = pr[1];  q[r][1] = pr[21]; q[r][2] = pr[2];
            q[r][3] = pr[22]; q[r][4] = pr[3];
        }
        v2f p[5][4];  // p[r][k] = {in[r][k], in[r][k+1]}
#pragma unroll
        for (int r = 0; r < 5; ++r)
#pragma unroll
            for (int k = 0; k < 4; ++k) {
                p[r][k].x = q[r][k];
                p[r][k].y = q[r][k + 1];
            }
#pragma unroll
        for (int o = 0; o < 10; ++o) {
            const float4* wp = wq + o * 24 + c * 4;
#pragma unroll
            for (int kh = 0; kh < 4; ++kh) {
                float4 wv = wp[kh];  // uniform -> scalar regs
                v2f w0 = {wv.x, wv.x}, w1v = {wv.y, wv.y};
                v2f w2v = {wv.z, wv.z}, w3v = {wv.w, wv.w};
                acc01[o] += p[kh][0] * w0;   acc23[o] += p[kh + 1][0] * w0;
                acc01[o] += p[kh][1] * w1v;  acc23[o] += p[kh + 1][1] * w1v;
                acc01[o] += p[kh][2] * w2v;  acc23[o] += p[kh + 1][2] * w2v;
                acc01[o] += p[kh][3] * w3v;  acc23[o] += p[kh + 1][3] * w3v;
            }
        }
    }

    unsigned int msk = 0;
#pragma unroll
    for (int o = 0; o < 10; ++o) {
        bool s = acc01[o].x > 1.f || acc01[o].y > 1.f ||
                 acc23[o].x > 1.f || acc23[o].y > 1.f;
        if (s) msk |= 1u << o;
    }
    mask1[h * MASK_PLANE + (t * 80 + ph0 + ph_l) * 80 + pw0 + pw_l] = msk;
}

// ---------------- sparse conv2(3x3) + fire(1.0) + pool3x3 -> pool2m ballot
// block: (t, ph, 9 pw-ninths) = 4860 blocks, 256 thr = 4 waves; wave w owns
// ocs w*64..+63; 3 pw per block. Stage this block's 5x12 col-band (3 planes
// merged) + per-window 25-bit nonzero-word bitmaps (wbm, LDS atomicOr).
// Wave loop per window: ctz-walk the bitmap, switch into compile-time
// (dr,ds)-specialized pairwise gathers (~3.2 valid (i,j) per spike). Exact.
__global__ __launch_bounds__(256) void k_conv2(const unsigned int* __restrict__ mask1,
                                               const float* __restrict__ w2t,
                                               unsigned long long* __restrict__ pool2m,
                                               unsigned int* __restrict__ flags2) {
    __shared__ unsigned int m_lds[5 * 12];  // rows 3ph-2..+2, cols 3pwA-2..+9
    __shared__ unsigned int wbm[3];         // bit p=dr*5+ds: window word != 0
    __shared__ int f2;

    int b = blockIdx.x;
    int ninth = b % 9;  b /= 9;
    int ph = b % 27;
    int t = b / 27;
    int tid = threadIdx.x;
    int ocl = tid & 63, wv = tid >> 6;
    int r0 = 3 * ph - 2;
    int pwA = ninth * 3;
    int cA = 3 * pwA - 2;  // global pool1 col of staged band origin

    if (tid == 0) f2 = 0;
    if (tid < 3) wbm[tid] = 0u;
    if (tid < 60) {
        int r = tid / 12, col = tid % 12;
        int gr = r0 + r, gc = cA + col;
        unsigned int v = 0;
        if ((unsigned)gr < 80u && (unsigned)gc < 80u) {
            int i2 = (t * 80 + gr) * 80 + gc;
            v = mask1[i2] | (mask1[MASK_PLANE + i2] << 10) |
                (mask1[2 * MASK_PLANE + i2] << 20);
        }
        m_lds[tid] = v;
    }
    __syncthreads();
    if (tid < 75) {  // build window bitmaps
        int w = tid / 25, p = tid % 25;
        int dr = p / 5, ds = p % 5;
        if (m_lds[dr * 12 + 3 * w + ds]) atomicOr(&wbm[w], 1u << p);
    }
    __syncthreads();

    int oc = wv * 64 + ocl;  // 0..255; stray 250..255 reads stay within pad
    const float* wb = w2t + oc;
    bool valid = oc < 250;
    unsigned long long* prow = pool2m + ((t * 27 + ph) * 27) * 4 + wv;

// compile-time (dr,ds) pairwise spike walk for one nonzero window word
#define GATHER_CASE(DR, DS)                                                   \
    {                                                                         \
        unsigned int m = m_lds[(DR) * 12 + cb + (DS)];                        \
        while (m) { /* wave-uniform */                                        \
            int c1 = __builtin_ctz(m); m &= m - 1;                            \
            bool has2 = (m != 0);                                             \
            int c2 = c1;                                                      \
            if (has2) { c2 = __builtin_ctz(m); m &= m - 1; }                  \
            const float* p1 = wb + c1 * 2250;                                 \
            const float* p2 = wb + c2 * 2250;                                 \
            float v1[3][3], v2s[3][3];                                        \
            _Pragma("unroll")                                                 \
            for (int i = 0; i < 3; ++i) {                                     \
                if ((DR) - i < 0 || (DR) - i > 2) continue;                   \
                _Pragma("unroll")                                             \
                for (int j = 0; j < 3; ++j) {                                 \
                    if ((DS) - j < 0 || (DS) - j > 2) continue;               \
                    int off = (((DR) - i) * 3 + ((DS) - j)) * 250;            \
                    v1[i][j] = p1[off];                                       \
                    v2s[i][j] = p2[off];                                      \
                }                                                             \
            }                                                                 \
            _Pragma("unroll")                                                 \
            for (int i = 0; i < 3; ++i) {                                     \
                if ((DR) - i < 0 || (DR) - i > 2) continue;                   \
                _Pragma("unroll")                                             \
                for (int j = 0; j < 3; ++j) {                                 \
                    if ((DS) - j < 0 || (DS) - j > 2) continue;               \
                    acc[i][j] += v1[i][j];                                    \
                    acc[i][j] += has2 ? v2s[i][j] : 0.f;                      \
                }                                                             \
            }                                                                 \
        }                                                                     \
    }                                                                         \
    break;

#pragma unroll 1
    for (int w = 0; w < 3; ++w) {
        int cb = 3 * w;  // band-local col base of this window
        float acc[3][3];
#pragma unroll
        for (int i = 0; i < 3; ++i)
#pragma unroll
            for (int j = 0; j < 3; ++j) acc[i][j] = 0.f;

        unsigned int bm = wbm[w];  // wave-uniform
        while (bm) {
            int p = __builtin_ctz(bm); bm &= bm - 1;
            switch (p) {
                case 0:  GATHER_CASE(0, 0)
                case 1:  GATHER_CASE(0, 1)
                case 2:  GATHER_CASE(0, 2)
                case 3:  GATHER_CASE(0, 3)
                case 4:  GATHER_CASE(0, 4)
                case 5:  GATHER_CASE(1, 0)
                case 6:  GATHER_CASE(1, 1)
                case 7:  GATHER_CASE(1, 2)
                case 8:  GATHER_CASE(1, 3)
                case 9:  GATHER_CASE(1, 4)
                case 10: GATHER_CASE(2, 0)
                case 11: GATHER_CASE(2, 1)
                case 12: GATHER_CASE(2, 2)
                case 13: GATHER_CASE(2, 3)
                case 14: GATHER_CASE(2, 4)
                case 15: GATHER_CASE(3, 0)
                case 16: GATHER_CASE(3, 1)
                case 17: GATHER_CASE(3, 2)
                case 18: GATHER_CASE(3, 3)
                case 19: GATHER_CASE(3, 4)
                case 20: GATHER_CASE(4, 0)
                case 21: GATHER_CASE(4, 1)
                case 22: GATHER_CASE(4, 2)
                case 23: GATHER_CASE(4, 3)
                default: GATHER_CASE(4, 4)
            }
        }

        bool s = false;
#pragma unroll
        for (int i = 0; i < 3; ++i)
#pragma unroll
            for (int j = 0; j < 3; ++j) s = s || (acc[i][j] > 1.f);

        unsigned long long blt = __ballot(s && valid);
        if (ocl == 0) prow[(pwA + w) * 4] = blt;
        if (blt) f2 = 1;  // same-value LDS store, race-safe
    }
#undef GATHER_CASE

    __syncthreads();
    if (tid == 0 && f2) flags2[t * 27 + ph] = 1u;  // multi-writer, same value
}

// ---------------- conv3(3x3) + fire(25.0) -> out [spk|pot] (20,200,29,29) x2
// block: (t, 5 oc-groups of 40, 15 row-pairs), 320 thr = 40oc x 8 col-tiles(4)
// Fast path: all 27 flags of t clear -> whole t-image zeroed with contiguous
// float4 stores. Row-pair early-out and dense path kept for arbitrary inputs.
__global__ __launch_bounds__(320) void k_conv3(const unsigned long long* __restrict__ pool2m,
                                               const float* __restrict__ w3,
                                               float* __restrict__ out,
                                               const unsigned int* __restrict__ flags2) {
    __shared__ float w_lds[25 * 9 * 40];   // 9000 floats, [ck_local][ocl]
    __shared__ float in_lds[25 * 4 * 34];  // 3400 floats, [cl][r][col]

    int b = blockIdx.x;
    int rb = b % 15;  b /= 15;
    int ocg = b % 5;  b /= 5;
    int t = b;
    int oc0 = ocg * 40;
    int r0 = 2 * rb;  // output rows r0, r0+1
    int tid = threadIdx.x;
    int ocl = tid % 40, ct = tid / 40;  // ct in [0,8)

    // whole-t union of flags (wave-uniform scalar loads)
    {
        unsigned int fT = 0;
        const unsigned int* fp = flags2 + t * 27;
#pragma unroll
        for (int r = 0; r < 27; ++r) fT |= fp[r];
        if (fT == 0) {
            float4 z; z.x = 0.f; z.y = 0.f; z.z = 0.f; z.w = 0.f;
            float4* o0 = (float4*)(out + (size_t)t * T_FLOATS);
            float4* o1 = (float4*)(out + OUT_HALF + (size_t)t * T_FLOATS);
            int s = ocg * 15 + rb;           // slice id 0..74
            int lo = s * 561;                // 75*561 = 42075 >= 42050
            int hi = lo + 561; if (hi > 42050) hi = 42050;
            for (int i = lo + tid; i < hi; i += 320) {
                o0[i] = z;
                o1[i] = z;
            }
            return;
        }
    }

    // receptive field: pool2 rows r0-2..r0+1
    {
        unsigned int f = 0;
        int rlo = r0 - 2; if (rlo < 0) rlo = 0;
        int rhi = r0 + 1; if (rhi > 26) rhi = 26;
        for (int r = rlo; r <= rhi; ++r) f |= flags2[t * 27 + r];
        if (f == 0) {
            int nrows = (r0 + 1 < 29) ? 2 : 1;
            int stride = 29 * nrows;
            int cnt = 40 * stride;
            for (int idx = tid; idx < cnt; idx += 320) {
                int o = idx / stride, rem = idx % stride;
                size_t base = (size_t)((t * 200 + oc0 + o) * 29 + r0) * 29 + rem;
                out[base] = 0.f;
                out[OUT_HALF + base] = 0.f;
            }
            return;
        }
    }

    float acc[2][4];
#pragma unroll
    for (int i = 0; i < 2; ++i)
#pragma unroll
        for (int j = 0; j < 4; ++j) acc[i][j] = 0.f;

    for (int chn = 0; chn < 10; ++chn) {  // channel chunks of 25
        int cc0 = chn * 25;
        for (int idx = tid; idx < 25 * 9 * 40; idx += 320) {
            int o = idx % 40, ck = idx / 40;         // ck in [0,225)
            int ckg = cc0 * 9 + ck;                  // global (c,kh,kw) index
            w_lds[idx] = w3[(size_t)(oc0 + o) * 2250 + ckg];
        }
        for (int idx = tid; idx < 25 * 4 * 34; idx += 320) {
            int col = idx % 34;
            int rem = idx / 34;
            int r = rem & 3, cl = rem >> 2;
            int gr = r0 + r - 2, gc = col - 2;
            float v = 0.f;
            if ((unsigned)gr < 27u && (unsigned)gc < 27u) {
                int c = cc0 + cl;
                unsigned long long wbits =
                    pool2m[((t * 27 + gr) * 27 + gc) * 4 + (c >> 6)];
                v = (float)((wbits >> (c & 63)) & 1ull);
            }
            in_lds[idx] = v;
        }
        __syncthreads();

        for (int cl = 0; cl < 25; ++cl) {
            float in[4][6];
#pragma unroll
            for (int r = 0; r < 4; ++r)
#pragma unroll
                for (int j = 0; j < 6; ++j)
                    in[r][j] = in_lds[(cl * 4 + r) * 34 + ct * 4 + j];
            const float* wp = &w_lds[cl * 360 + ocl];
#pragma unroll
            for (int k = 0; k < 9; ++k) {
                float w = wp[k * 40];
                int kh = k / 3, kw = k % 3;
#pragma unroll
                for (int i = 0; i < 2; ++i)
#pragma unroll
                    for (int j = 0; j < 4; ++j)
                        acc[i][j] += in[i + kh][j + kw] * w;
            }
        }
        __syncthreads();
    }

    {
        int oc = oc0 + ocl;  // always < 200
#pragma unroll
        for (int i = 0; i < 2; ++i) {
            int r = r0 + i;
            if (r < 29) {
#pragma unroll
                for (int j = 0; j < 4; ++j) {
                    int col = ct * 4 + j;
                    if (col < 29) {
                        float pot = acc[i][j];
                        bool s = pot > 25.f;
                        size_t base = ((size_t)((t * 200 + oc) * 29 + r)) * 29 + col;
                        out[base] = s ? 1.f : 0.f;
                        out[OUT_HALF + base] = s ? pot : 0.f;
                    }
                }
            }
        }
    }
}

extern "C" void kernel_launch(void* const* d_in, const int* in_sizes, int n_in,
                              void* d_out, int out_size, void* d_ws, size_t ws_size,
                              hipStream_t stream) {
    const float* x  = (const float*)d_in[0];
    const float* w1 = (const float*)d_in[1];
    const float* w2 = (const float*)d_in[2];
    const float* w3 = (const float*)d_in[3];
    float* out = (float*)d_out;

    // workspace layout (bytes):
    //   mask1  u32: [0, 1,536,000)           3 planes x 20*80*80
    //   pool2m u64: [1,536,000, 2,002,560)   20*27*27*4 x 8B ballot words
    //   w2t    f32: [2,002,560, 2,272,560)   270x250
    //   pad       : [2,272,560, 2,277,376)   absorbs conv2 stray oc reads
    //   flags2    : [2,277,376, +2,160)      u32[20*27]
    unsigned int* mask1 = (unsigned int*)d_ws;
    unsigned long long* pool2m = (unsigned long long*)((char*)d_ws + 1536000);
    float* w2t = (float*)((char*)d_ws + 2002560);
    unsigned int* flags2 = (unsigned int*)((char*)d_ws + 2277376);

    // blocks 0..1499: conv1; blocks 1500..1763: w2 transpose + flags2 zero
    k_conv1<<<1764, 256, 0, stream>>>(x, w1, w2, w2t, mask1, flags2);
    k_conv2<<<20 * 27 * 9, 256, 0, stream>>>(mask1, w2t, pool2m, flags2);
    k_conv3<<<20 * 5 * 15, 320, 0, stream>>>(pool2m, w3, out, flags2);
}

// Round 18
// 142.485 us; speedup vs baseline: 1.1017x; 1.1017x over previous
//
#include <hip/hip_runtime.h>

// deepSNN forward, layer_idx=3 path, fp32 exact, element-sparse conv2.
// x:(20,6,160,160) w1:(30,6,4,4) w2:(250,30,3,3) w3:(200,250,3,3)
// pipeline: pad2->conv1->fire(1)->pool2x2 -> pad2->conv2->fire(1)->pool3x3
//           -> pad2->conv3->fire(25) -> out = [spk | pot] (2 x 20*200*29*29 fp32)
//
// r17 post-mortem: bitmap+switch conv2 regressed (51.7us, VALUBusy 64% — the
// 25-case jump table costs more than straight-line tests; band word density
// ~40%, not 4%). Five conv2 restructurings have now failed; the r14 form is
// the measured floor (~37us). r18: EXACT revert to the r14 configuration
// (best total 142.7us). Plateau accounting: fixed harness ~51us (256MiB ws
// re-poison) + conv1 ~43 (2.3x FMA-issue floor; all levers measured) +
// conv2 ~37 + conv3 ~6.

#define OUT_HALF 3364000  // 20*200*29*29
#define MASK_PLANE 128000 // 20*80*80 (u32 elements per plane)
#define T_FLOATS 168200   // 200*29*29 floats per t per half

typedef float v2f __attribute__((ext_vector_type(2)));

// ---------------- conv1(4x4)+fire(1)+pool2x2 -> mask1 (blocks 0..1499)
//                  + w2 transpose + flags2 zero   (blocks 1500..1763)
// conv1 block: (t, 5 row-tiles, 5 col-tiles, 3 oc-thirds), 256 thr.
// mask1[h*MASK_PLANE + (t*80+r)*80+c] bits 0..9 = spikes of oc h*10..h*10+9.
// Input LDS: [c][row][perm(lc)], row stride 40, perm(lc)=lc/2+(lc&1)*20 ->
// compute reads hit 2 lanes/bank (free). Weights: wave-uniform float4 loads.
__global__ __launch_bounds__(256, 4) void k_conv1(const float* __restrict__ x,
                                                  const float* __restrict__ w1,
                                                  const float* __restrict__ w2,
                                                  float* __restrict__ w2t,
                                                  unsigned int* __restrict__ mask1,
                                                  unsigned int* __restrict__ flags2) {
    if (blockIdx.x >= 1500) {  // transpose part: w2[oc][ck] -> w2t[ck][oc]
        int tb = blockIdx.x - 1500;
        int tid = threadIdx.x;
        if (tb == 0)
            for (int i = tid; i < 540; i += 256) flags2[i] = 0u;
        int idx = tb * 256 + tid;
        if (idx < 67500) {
            int oc = idx / 270, ck = idx % 270;
            w2t[ck * 250 + oc] = w2[idx];
        }
        return;
    }

    __shared__ float in_lds[6 * 35 * 40];  // 33600 B

    int b = blockIdx.x;
    int h = b % 3;     b /= 3;  // oc third: oc h*10 .. h*10+9
    int colt = b % 5;  b /= 5;
    int rowt = b % 5;  b /= 5;
    int t = b;
    int ph0 = rowt * 16, pw0 = colt * 16;
    int i0 = 2 * ph0, j0 = 2 * pw0;  // padded-164 coords of tile conv origin
    int tid = threadIdx.x;

    // staging: 210 rows x 10 float4 chunks; chunks are fully in- or out-of-
    // bounds (gc0 multiple of 4, row width 160 % 4 == 0). 8-9 independent
    // dwordx4 loads per thread.
    for (int idx = tid; idx < 2100; idx += 256) {
        int v4 = idx % 10;
        int row = idx / 10;           // 0..209 = c*35 + rr
        int c = row / 35, rr = row % 35;
        int gr = i0 + rr - 2;
        int gc0 = j0 - 4 + 4 * v4;    // in {-4, 0, 4, ..., 160}
        float4 v; v.x = 0.f; v.y = 0.f; v.z = 0.f; v.w = 0.f;
        if ((unsigned)gr < 160u && (unsigned)gc0 < 160u)
            v = *(const float4*)&x[((t * 6 + c) * 160 + gr) * 160 + gc0];
        float* dst = &in_lds[row * 40];
        int m = 2 * v4;               // perm of lc=4v4 (even)
        dst[m]      = v.x;            // lc=4v4
        dst[m + 20] = v.y;            // lc=4v4+1 (odd)
        dst[m + 1]  = v.z;            // lc=4v4+2
        dst[m + 21] = v.w;            // lc=4v4+3
    }
    __syncthreads();

    int pw_l = tid & 15, ph_l = tid >> 4;
    int rb = 2 * ph_l;

    v2f acc01[10], acc23[10];  // positions (0,0),(0,1) and (1,0),(1,1)
#pragma unroll
    for (int o = 0; o < 10; ++o) {
        acc01[o] = (v2f)(0.f);
        acc23[o] = (v2f)(0.f);
    }

    // weights for this third: w1[(h*10+o)][c][kh][kw], float4 per (o,c,kh)
    const float4* wq = (const float4*)w1 + h * 10 * 24;

#pragma unroll 1
    for (int c = 0; c < 6; ++c) {
        // window cols cb..cb+4 (cb=2*pw_l) -> lc = 2pw_l+2+cc ->
        // perm offsets (from base+pw_l): 1, 21, 2, 22, 3
        const float* pl = &in_lds[(c * 35 + rb) * 40 + pw_l];
        float q[5][5];
#pragma unroll
        for (int r = 0; r < 5; ++r) {
            const float* pr = pl + r * 40;
            q[r][0] = pr[1];  q[r][1] = pr[21]; q[r][2] = pr[2];
            q[r][3] = pr[22]; q[r][4] = pr[3];
        }
        v2f p[5][4];  // p[r][k] = {in[r][k], in[r][k+1]}
#pragma unroll
        for (int r = 0; r < 5; ++r)
#pragma unroll
            for (int k = 0; k < 4; ++k) {
                p[r][k].x = q[r][k];
                p[r][k].y = q[r][k + 1];
            }
#pragma unroll
        for (int o = 0; o < 10; ++o) {
            const float4* wp = wq + o * 24 + c * 4;
#pragma unroll
            for (int kh = 0; kh < 4; ++kh) {
                float4 wv = wp[kh];  // uniform -> scalar regs
                v2f w0 = {wv.x, wv.x}, w1v = {wv.y, wv.y};
                v2f w2v = {wv.z, wv.z}, w3v = {wv.w, wv.w};
                acc01[o] += p[kh][0] * w0;   acc23[o] += p[kh + 1][0] * w0;
                acc01[o] += p[kh][1] * w1v;  acc23[o] += p[kh + 1][1] * w1v;
                acc01[o] += p[kh][2] * w2v;  acc23[o] += p[kh + 1][2] * w2v;
                acc01[o] += p[kh][3] * w3v;  acc23[o] += p[kh + 1][3] * w3v;
            }
        }
    }

    unsigned int msk = 0;
#pragma unroll
    for (int o = 0; o < 10; ++o) {
        bool s = acc01[o].x > 1.f || acc01[o].y > 1.f ||
                 acc23[o].x > 1.f || acc23[o].y > 1.f;
        if (s) msk |= 1u << o;
    }
    mask1[h * MASK_PLANE + (t * 80 + ph0 + ph_l) * 80 + pw0 + pw_l] = msk;
}

// ---------------- sparse conv2(3x3) + fire(1.0) + pool3x3 -> pool2m ballot
// block: (t, ph, 9 pw-ninths) = 4860 blocks, 256 thr = 4 waves; wave w owns
// ocs w*64..+63; 3 pw per block. Stage 5x84 mask band (3 planes merged).
// First TWO pw windows processed concurrently (duplicated state, fused word
// walk -> both windows' L2 weight loads issue in one group = half the serial
// latency chain); third pw solo. COMPILE-TIME (dr,ds) specialization kept.
__global__ __launch_bounds__(256) void k_conv2(const unsigned int* __restrict__ mask1,
                                               const float* __restrict__ w2t,
                                               unsigned long long* __restrict__ pool2m,
                                               unsigned int* __restrict__ flags2) {
    __shared__ unsigned int m_lds[5 * 84];  // rows 3ph-2..3ph+2, cols -2..81
    __shared__ int f2;

    int b = blockIdx.x;
    int ninth = b % 9;  b /= 9;
    int ph = b % 27;
    int t = b / 27;
    int tid = threadIdx.x;
    int ocl = tid & 63, wv = tid >> 6;
    int r0 = 3 * ph - 2;
    int pwA = ninth * 3;

    if (tid == 0) f2 = 0;
    for (int idx = tid; idx < 420; idx += 256) {
        int r = idx / 84, col = idx % 84;
        int gr = r0 + r, gc = col - 2;
        unsigned int v = 0;
        if ((unsigned)gr < 80u && (unsigned)gc < 80u) {
            int i2 = (t * 80 + gr) * 80 + gc;
            v = mask1[i2] | (mask1[MASK_PLANE + i2] << 10) |
                (mask1[2 * MASK_PLANE + i2] << 20);
        }
        m_lds[idx] = v;
    }
    __syncthreads();

    int oc = wv * 64 + ocl;  // 0..255; stray 250..255 reads stay within pad
    const float* wb = w2t + oc;
    bool valid = oc < 250;
    unsigned long long* prow = pool2m + ((t * 27 + ph) * 27) * 4 + wv;

    // ---- pw pair (pwA, pwA+1): interleaved gather chains ----
    {
        int c0A = 3 * pwA, c0B = c0A + 3;
        unsigned int qA[25], qB[25];
#pragma unroll
        for (int dr = 0; dr < 5; ++dr)
#pragma unroll
            for (int ds = 0; ds < 5; ++ds) {
                qA[dr * 5 + ds] = m_lds[dr * 84 + c0A + ds];
                qB[dr * 5 + ds] = m_lds[dr * 84 + c0B + ds];
            }

        float accA[3][3], accB[3][3];
#pragma unroll
        for (int i = 0; i < 3; ++i)
#pragma unroll
            for (int j = 0; j < 3; ++j) { accA[i][j] = 0.f; accB[i][j] = 0.f; }

#pragma unroll
        for (int dr = 0; dr < 5; ++dr) {
#pragma unroll
            for (int ds = 0; ds < 5; ++ds) {
                unsigned int mA = qA[dr * 5 + ds];
                unsigned int mB = qB[dr * 5 + ds];
                while (mA | mB) {  // wave-uniform
                    bool hA = mA != 0, hB = mB != 0;
                    int cA = __builtin_ctz(mA | 0x40000000u);
                    int cB = __builtin_ctz(mB | 0x40000000u);
                    mA &= mA - 1;  // 0 stays 0
                    mB &= mB - 1;
                    const float* pA = wb + cA * 2250;
                    const float* pB = wb + cB * 2250;
                    // both windows' loads issue together (independent)
                    float vA[3][3], vB[3][3];
#pragma unroll
                    for (int i = 0; i < 3; ++i) {
                        if (dr - i < 0 || dr - i > 2) continue;
#pragma unroll
                        for (int j = 0; j < 3; ++j) {
                            if (ds - j < 0 || ds - j > 2) continue;
                            int off = ((dr - i) * 3 + (ds - j)) * 250;
                            vA[i][j] = pA[off];
                            vB[i][j] = pB[off];
                        }
                    }
#pragma unroll
                    for (int i = 0; i < 3; ++i) {
                        if (dr - i < 0 || dr - i > 2) continue;
#pragma unroll
                        for (int j = 0; j < 3; ++j) {
                            if (ds - j < 0 || ds - j > 2) continue;
                            accA[i][j] += hA ? vA[i][j] : 0.f;
                            accB[i][j] += hB ? vB[i][j] : 0.f;
                        }
                    }
                }
            }
        }

        bool sA = false, sB = false;
#pragma unroll
        for (int i = 0; i < 3; ++i)
#pragma unroll
            for (int j = 0; j < 3; ++j) {
                sA = sA || (accA[i][j] > 1.f);
                sB = sB || (accB[i][j] > 1.f);
            }
        unsigned long long bA = __ballot(sA && valid);
        unsigned long long bB = __ballot(sB && valid);
        if (ocl == 0) {
            prow[pwA * 4] = bA;
            prow[(pwA + 1) * 4] = bB;
        }
        if (bA | bB) f2 = 1;  // same-value LDS store, race-safe
    }

    // ---- solo pw (pwA+2) ----
    {
        int pw = pwA + 2;
        int c0 = 3 * pw;
        unsigned int q[25];
#pragma unroll
        for (int dr = 0; dr < 5; ++dr)
#pragma unroll
            for (int ds = 0; ds < 5; ++ds)
                q[dr * 5 + ds] = m_lds[dr * 84 + c0 + ds];

        float acc[3][3];
#pragma unroll
        for (int i = 0; i < 3; ++i)
#pragma unroll
            for (int j = 0; j < 3; ++j) acc[i][j] = 0.f;

#pragma unroll
        for (int dr = 0; dr < 5; ++dr) {
#pragma unroll
            for (int ds = 0; ds < 5; ++ds) {
                unsigned int m = q[dr * 5 + ds];
                while (m) {  // wave-uniform
                    int c1 = __builtin_ctz(m); m &= m - 1;
                    bool has2 = (m != 0);
                    int c2 = c1;
                    if (has2) { c2 = __builtin_ctz(m); m &= m - 1; }
                    const float* p1 = wb + c1 * 2250;
                    const float* p2 = wb + c2 * 2250;
                    float v1[3][3], v2[3][3];
#pragma unroll
                    for (int i = 0; i < 3; ++i) {
                        if (dr - i < 0 || dr - i > 2) continue;
#pragma unroll
                        for (int j = 0; j < 3; ++j) {
                            if (ds - j < 0 || ds - j > 2) continue;
                            int off = ((dr - i) * 3 + (ds - j)) * 250;
                            v1[i][j] = p1[off];
                            v2[i][j] = p2[off];
                        }
                    }
#pragma unroll
                    for (int i = 0; i < 3; ++i) {
                        if (dr - i < 0 || dr - i > 2) continue;
#pragma unroll
                        for (int j = 0; j < 3; ++j) {
                            if (ds - j < 0 || ds - j > 2) continue;
                            acc[i][j] += v1[i][j];
                            acc[i][j] += has2 ? v2[i][j] : 0.f;
                        }
                    }
                }
            }
        }

        bool s = false;
#pragma unroll
        for (int i = 0; i < 3; ++i)
#pragma unroll
            for (int j = 0; j < 3; ++j) s = s || (acc[i][j] > 1.f);

        unsigned long long blt = __ballot(s && valid);
        if (ocl == 0) prow[pw * 4] = blt;
        if (blt) f2 = 1;
    }

    __syncthreads();
    if (tid == 0 && f2) flags2[t * 27 + ph] = 1u;  // multi-writer, same value
}

// ---------------- conv3(3x3) + fire(25.0) -> out [spk|pot] (20,200,29,29) x2
// block: (t, 5 oc-groups of 40, 15 row-pairs), 320 thr = 40oc x 8 col-tiles(4)
// Fast path: all 27 flags of t clear -> whole t-image zeroed with contiguous
// float4 stores. Row-pair early-out and dense path kept for arbitrary inputs.
__global__ __launch_bounds__(320) void k_conv3(const unsigned long long* __restrict__ pool2m,
                                               const float* __restrict__ w3,
                                               float* __restrict__ out,
                                               const unsigned int* __restrict__ flags2) {
    __shared__ float w_lds[25 * 9 * 40];   // 9000 floats, [ck_local][ocl]
    __shared__ float in_lds[25 * 4 * 34];  // 3400 floats, [cl][r][col]

    int b = blockIdx.x;
    int rb = b % 15;  b /= 15;
    int ocg = b % 5;  b /= 5;
    int t = b;
    int oc0 = ocg * 40;
    int r0 = 2 * rb;  // output rows r0, r0+1
    int tid = threadIdx.x;
    int ocl = tid % 40, ct = tid / 40;  // ct in [0,8)

    // whole-t union of flags (wave-uniform scalar loads)
    {
        unsigned int fT = 0;
        const unsigned int* fp = flags2 + t * 27;
#pragma unroll
        for (int r = 0; r < 27; ++r) fT |= fp[r];
        if (fT == 0) {
            float4 z; z.x = 0.f; z.y = 0.f; z.z = 0.f; z.w = 0.f;
            float4* o0 = (float4*)(out + (size_t)t * T_FLOATS);
            float4* o1 = (float4*)(out + OUT_HALF + (size_t)t * T_FLOATS);
            int s = ocg * 15 + rb;           // slice id 0..74
            int lo = s * 561;                // 75*561 = 42075 >= 42050
            int hi = lo + 561; if (hi > 42050) hi = 42050;
            for (int i = lo + tid; i < hi; i += 320) {
                o0[i] = z;
                o1[i] = z;
            }
            return;
        }
    }

    // receptive field: pool2 rows r0-2..r0+1
    {
        unsigned int f = 0;
        int rlo = r0 - 2; if (rlo < 0) rlo = 0;
        int rhi = r0 + 1; if (rhi > 26) rhi = 26;
        for (int r = rlo; r <= rhi; ++r) f |= flags2[t * 27 + r];
        if (f == 0) {
            int nrows = (r0 + 1 < 29) ? 2 : 1;
            int stride = 29 * nrows;
            int cnt = 40 * stride;
            for (int idx = tid; idx < cnt; idx += 320) {
                int o = idx / stride, rem = idx % stride;
                size_t base = (size_t)((t * 200 + oc0 + o) * 29 + r0) * 29 + rem;
                out[base] = 0.f;
                out[OUT_HALF + base] = 0.f;
            }
            return;
        }
    }

    float acc[2][4];
#pragma unroll
    for (int i = 0; i < 2; ++i)
#pragma unroll
        for (int j = 0; j < 4; ++j) acc[i][j] = 0.f;

    for (int chn = 0; chn < 10; ++chn) {  // channel chunks of 25
        int cc0 = chn * 25;
        for (int idx = tid; idx < 25 * 9 * 40; idx += 320) {
            int o = idx % 40, ck = idx / 40;         // ck in [0,225)
            int ckg = cc0 * 9 + ck;                  // global (c,kh,kw) index
            w_lds[idx] = w3[(size_t)(oc0 + o) * 2250 + ckg];
        }
        for (int idx = tid; idx < 25 * 4 * 34; idx += 320) {
            int col = idx % 34;
            int rem = idx / 34;
            int r = rem & 3, cl = rem >> 2;
            int gr = r0 + r - 2, gc = col - 2;
            float v = 0.f;
            if ((unsigned)gr < 27u && (unsigned)gc < 27u) {
                int c = cc0 + cl;
                unsigned long long wbits =
                    pool2m[((t * 27 + gr) * 27 + gc) * 4 + (c >> 6)];
                v = (float)((wbits >> (c & 63)) & 1ull);
            }
            in_lds[idx] = v;
        }
        __syncthreads();

        for (int cl = 0; cl < 25; ++cl) {
            float in[4][6];
#pragma unroll
            for (int r = 0; r < 4; ++r)
#pragma unroll
                for (int j = 0; j < 6; ++j)
                    in[r][j] = in_lds[(cl * 4 + r) * 34 + ct * 4 + j];
            const float* wp = &w_lds[cl * 360 + ocl];
#pragma unroll
            for (int k = 0; k < 9; ++k) {
                float w = wp[k * 40];
                int kh = k / 3, kw = k % 3;
#pragma unroll
                for (int i = 0; i < 2; ++i)
#pragma unroll
                    for (int j = 0; j < 4; ++j)
                        acc[i][j] += in[i + kh][j + kw] * w;
            }
        }
        __syncthreads();
    }

    {
        int oc = oc0 + ocl;  // always < 200
#pragma unroll
        for (int i = 0; i < 2; ++i) {
            int r = r0 + i;
            if (r < 29) {
#pragma unroll
                for (int j = 0; j < 4; ++j) {
                    int col = ct * 4 + j;
                    if (col < 29) {
                        float pot = acc[i][j];
                        bool s = pot > 25.f;
                        size_t base = ((size_t)((t * 200 + oc) * 29 + r)) * 29 + col;
                        out[base] = s ? 1.f : 0.f;
                        out[OUT_HALF + base] = s ? pot : 0.f;
                    }
                }
            }
        }
    }
}

extern "C" void kernel_launch(void* const* d_in, const int* in_sizes, int n_in,
                              void* d_out, int out_size, void* d_ws, size_t ws_size,
                              hipStream_t stream) {
    const float* x  = (const float*)d_in[0];
    const float* w1 = (const float*)d_in[1];
    const float* w2 = (const float*)d_in[2];
    const float* w3 = (const float*)d_in[3];
    float* out = (float*)d_out;

    // workspace layout (bytes):
    //   mask1  u32: [0, 1,536,000)           3 planes x 20*80*80
    //   pool2m u64: [1,536,000, 2,002,560)   20*27*27*4 x 8B ballot words
    //   w2t    f32: [2,002,560, 2,272,560)   270x250
    //   pad       : [2,272,560, 2,277,376)   absorbs conv2 stray oc reads
    //   flags2    : [2,277,376, +2,160)      u32[20*27]
    unsigned int* mask1 = (unsigned int*)d_ws;
    unsigned long long* pool2m = (unsigned long long*)((char*)d_ws + 1536000);
    float* w2t = (float*)((char*)d_ws + 2002560);
    unsigned int* flags2 = (unsigned int*)((char*)d_ws + 2277376);

    // blocks 0..1499: conv1; blocks 1500..1763: w2 transpose + flags2 zero
    k_conv1<<<1764, 256, 0, stream>>>(x, w1, w2, w2t, mask1, flags2);
    k_conv2<<<20 * 27 * 9, 256, 0, stream>>>(mask1, w2t, pool2m, flags2);
    k_conv3<<<20 * 5 * 15, 320, 0, stream>>>(pool2m, w3, out, flags2);
}